// Round 6
// baseline (816.822 us; speedup 1.0000x reference)
//
#include <hip/hip_runtime.h>

#define NEG_INF (-3.402823466e+38f)

typedef __bf16 bf16x8 __attribute__((ext_vector_type(8)));
typedef float  f32x16 __attribute__((ext_vector_type(16)));

__device__ __forceinline__ unsigned short f2bf(float f){
    unsigned u = __builtin_bit_cast(unsigned, f);
    u += 0x7fffu + ((u >> 16) & 1u);
    return (unsigned short)(u >> 16);
}
__device__ __forceinline__ float bf2f(unsigned short h){
    unsigned u = ((unsigned)h) << 16;
    return __builtin_bit_cast(float, u);
}

#if defined(__has_builtin)
#if __has_builtin(__builtin_amdgcn_global_load_lds)
#define ASYNC_CP 1
#endif
#endif

// async global->LDS: per-lane g, wave-uniform lbase; lane i lands at lbase + i*16B
__device__ __forceinline__ void gl_lds(const unsigned short* g, unsigned short* lbase, int lane) {
#ifdef ASYNC_CP
    __builtin_amdgcn_global_load_lds(
        (const __attribute__((address_space(1))) unsigned int*)g,
        (__attribute__((address_space(3))) unsigned int*)lbase, 16, 0, 0);
#else
    *(uint4*)(lbase + (size_t)lane * 8) = *(const uint4*)g;
#endif
}

// ---------------- prep: x fp32 NCHW -> bf16 NHWC -------------------
__global__ void __launch_bounds__(256)
k_xpose(const float* __restrict__ x, unsigned short* __restrict__ xh)
{
    __shared__ float tile[64 * 129];
    const int t = threadIdx.x;
    const int ci0 = blockIdx.x * 64, h = blockIdx.y, b = blockIdx.z;
    const float4* src = (const float4*)x;
#pragma unroll
    for (int i = 0; i < 8; ++i) {
        int idx = t + i * 256;
        int ci = idx >> 5, w4 = idx & 31;
        float4 v = src[((b * 256 + ci0 + ci) * 128 + h) * 32 + w4];
        tile[ci * 129 + w4 * 4 + 0] = v.x;
        tile[ci * 129 + w4 * 4 + 1] = v.y;
        tile[ci * 129 + w4 * 4 + 2] = v.z;
        tile[ci * 129 + w4 * 4 + 3] = v.w;
    }
    __syncthreads();
    unsigned* dst = (unsigned*)xh;
#pragma unroll
    for (int i = 0; i < 16; ++i) {
        int idx = t + i * 256;
        int w = idx >> 5, cp = idx & 31;
        float lo = tile[(cp * 2 + 0) * 129 + w];
        float hi = tile[(cp * 2 + 1) * 129 + w];
        dst[((b * 128 + h) * 128 + w) * 128 + (ci0 >> 1) + cp] =
            (unsigned)f2bf(lo) | ((unsigned)f2bf(hi) << 16);
    }
}

// ---------------- prep: weight packing (BN scale folded) -----------
__global__ void __launch_bounds__(256)
k_wpack(const float* __restrict__ wl, const float* __restrict__ sl, const float* __restrict__ ol,
        const float* __restrict__ wr, const float* __restrict__ sr, const float* __restrict__ orr,
        const float* __restrict__ wt, const float* __restrict__ st, const float* __restrict__ ot,
        const float* __restrict__ wb, const float* __restrict__ sb, const float* __restrict__ ob,
        const float* __restrict__ w2, const float* __restrict__ s2, const float* __restrict__ o2,
        const float* __restrict__ w1, const float* __restrict__ s1, const float* __restrict__ o1,
        unsigned short* __restrict__ wpkBR, unsigned short* __restrict__ wpk2,
        unsigned short* __restrict__ wpk1, float* __restrict__ shF, float* __restrict__ obF)
{
    int i = blockIdx.x * 256 + threadIdx.x;
    if (i < 1179648) {
        int br = i / 294912, r = i % 294912;
        int c = r / 2304, r2 = r % 2304, ci = r2 / 9, k9 = r2 % 9;
        const float* wp = br == 0 ? wl : br == 1 ? wr : br == 2 ? wt : wb;
        const float* sp = br == 0 ? sl : br == 1 ? sr : br == 2 ? st : sb;
        float v = wp[r] * sp[c];
        int p = (c >> 4) * 64 + br * 16 + (c & 15);
        wpkBR[(((((ci >> 4) * 9 + k9) * 2 + ((ci >> 3) & 1)) * 512 + p) * 8) + (ci & 7)] = f2bf(v);
    } else if (i < 1474560) {
        int j = i - 1179648;
        int c = j / 1152, r2 = j % 1152, ci = r2 / 9, k9 = r2 % 9;
        wpk2[(((((ci >> 4) * 9 + k9) * 2 + ((ci >> 3) & 1)) * 256 + c) * 8) + (ci & 7)] = f2bf(w2[j] * s2[c]);
    } else if (i < 1540096) {
        int j = i - 1474560;
        int c = j >> 8, ci = j & 255;
        wpk1[((((ci >> 4) * 2 + ((ci >> 3) & 1)) * 256 + c) * 8) + (ci & 7)] = f2bf(w1[j] * s1[c]);
    } else if (i < 1540608) {
        int p = i - 1540096;
        int br = (p >> 4) & 3, c = (p >> 6) * 16 + (p & 15);
        const float* op = br == 0 ? ol : br == 1 ? orr : br == 2 ? ot : ob;
        shF[p] = op[c];
    } else if (i < 1540864) {
        int c = i - 1540608;
        obF[c] = o2[c] + o1[c];
    }
}

// ---------------- branch conv: all 4 branches, 4 rows/block --------
// ROUND-2 STRUCTURE (measured 312/310us, MfmaUtil 47%): xin double-buffered
// (gl_lds 2-phase prefetch), weights DMA'd to LDS wbuf once per chunk and
// broadcast to all 4 waves; next chunk's weights reg-staged during compute,
// written to wbuf between the two barriers.
// A/B evidence (r4): direct global->reg A-frags = 347us (L1 thrash). Keep wbuf.
// __launch_bounds__(256,2): (256,3) caps regs at 170 -> acc spills ->
// 2.7GB scratch, 3.3x slower (r3 lesson). Do NOT raise.
// NEW (r6): s_setprio(1) around MFMA cluster (T5) -- the 2 co-resident
// blocks run unsynced chunk phases, so the CU scheduler has role diversity.
#define XIN_SH 12672
#define WBUF_SH 9216
__global__ void __launch_bounds__(256, 2)
k_brconv(const unsigned short* __restrict__ xh, const unsigned short* __restrict__ wpkBR,
         const float* __restrict__ shF, unsigned short* __restrict__ sbuf2,
         unsigned short* __restrict__ ytbT, unsigned short* __restrict__ ytbB)
{
    __shared__ __align__(16) unsigned short smem[2 * XIN_SH + WBUF_SH + 128];
    unsigned short* xinA = smem;
    unsigned short* xinB = smem + XIN_SH;
    unsigned short* wbuf = smem + 2 * XIN_SH;
    float* shs = (float*)(smem + 2 * XIN_SH + WBUF_SH);

    const int t = threadIdx.x;
    // XCD-aware bijective swizzle (nwg=2048): XCD j works batch b=j; co-resident
    // blocks on one XCD share xin strips + all weight slices in L2.
    const int lin = (int)blockIdx.x + ((int)blockIdx.y << 3) + ((int)blockIdx.z << 8);
    const int swz = (lin & 7) * 256 + (lin >> 3);
    const int bx = swz & 7, h0 = ((swz >> 3) & 31) << 2, b = swz >> 8;
    const int wv = t >> 6, lane = t & 63;
    const int lo5 = lane & 31, hi1 = lane >> 5;
    const int hi32 = lane & 32;

    if (t < 64) shs[t] = shF[bx * 64 + t];
    // zero BOTH xin buffers once: halo cols + OOB rows stay zero forever
    for (int idx = t; idx < 3168; idx += 256)
        *(uint4*)(smem + idx * 8) = make_uint4(0, 0, 0, 0);

    f32x16 acc[2][4];
#pragma unroll
    for (int ct = 0; ct < 2; ++ct)
#pragma unroll
        for (int nb = 0; nb < 4; ++nb)
#pragma unroll
            for (int i = 0; i < 16; ++i) acc[ct][nb][i] = 0.f;

    __syncthreads();   // zero-init visible before async stores land

    // ---- prologue: stage chunk 0 (xin + weights via gl_lds) ----
    for (int s = wv; s < 24; s += 4) {
        int r = s >> 2, khi = (s >> 1) & 1, half = s & 1;
        int ih = h0 - 1 + r;
        if (ih >= 0 && ih < 128)
            gl_lds(xh + (((size_t)(b * 128 + ih) * 128 + half * 64 + lane) * 256) + khi * 8,
                   xinA + ((r * 2 + khi) * 132 + 1 + half * 64) * 8, lane);
    }
    for (int s = wv; s < 18; s += 4)
        gl_lds(wpkBR + ((size_t)s * 512 + bx * 64 + lane) * 8, wbuf + s * 512, lane);
    __syncthreads();

    uint4 wr0 = make_uint4(0, 0, 0, 0), wr1 = wr0, wr2 = wr0, wr3 = wr0, wr4 = wr0;
    unsigned short* xcur = xinA;
    unsigned short* xnxt = xinB;

    for (int cb = 0; cb < 16; ++cb) {
        // issue next-chunk staging BEFORE compute -> overlaps with MFMA phase
        if (cb < 15) {
            const int nc = cb + 1;
            for (int s = wv; s < 24; s += 4) {
                int r = s >> 2, khi = (s >> 1) & 1, half = s & 1;
                int ih = h0 - 1 + r;
                if (ih >= 0 && ih < 128)
                    gl_lds(xh + (((size_t)(b * 128 + ih) * 128 + half * 64 + lane) * 256) + nc * 16 + khi * 8,
                           xnxt + ((r * 2 + khi) * 132 + 1 + half * 64) * 8, lane);
            }
            wr0 = *(const uint4*)(wpkBR + ((size_t)(nc * 18 + wv) * 512 + bx * 64 + lane) * 8);
            wr1 = *(const uint4*)(wpkBR + ((size_t)(nc * 18 + wv + 4) * 512 + bx * 64 + lane) * 8);
            wr2 = *(const uint4*)(wpkBR + ((size_t)(nc * 18 + wv + 8) * 512 + bx * 64 + lane) * 8);
            wr3 = *(const uint4*)(wpkBR + ((size_t)(nc * 18 + wv + 12) * 512 + bx * 64 + lane) * 8);
            if (wv < 2)
                wr4 = *(const uint4*)(wpkBR + ((size_t)(nc * 18 + wv + 16) * 512 + bx * 64 + lane) * 8);
        }
        __builtin_amdgcn_s_setprio(1);
#pragma unroll
        for (int k9 = 0; k9 < 9; ++k9) {
            const int kh = k9 / 3, kw = k9 % 3;
            bf16x8 a0 = *(const bf16x8*)(wbuf + ((k9 * 2 + hi1) * 64 + lo5) * 8);
            bf16x8 a1 = *(const bf16x8*)(wbuf + ((k9 * 2 + hi1) * 64 + 32 + lo5) * 8);
#pragma unroll
            for (int nb = 0; nb < 4; ++nb) {
                bf16x8 bf = *(const bf16x8*)(xcur + (((wv + kh) * 2 + hi1) * 132 + nb * 32 + lo5 + kw) * 8);
                acc[0][nb] = __builtin_amdgcn_mfma_f32_32x32x16_bf16(a0, bf, acc[0][nb], 0, 0, 0);
                acc[1][nb] = __builtin_amdgcn_mfma_f32_32x32x16_bf16(a1, bf, acc[1][nb], 0, 0, 0);
            }
        }
        __builtin_amdgcn_s_setprio(0);
        __syncthreads();   // drains overlapped vmcnt; all waves done reading wbuf
        if (cb < 15) {
            *(uint4*)(wbuf + (wv) * 512 + lane * 8) = wr0;
            *(uint4*)(wbuf + (wv + 4) * 512 + lane * 8) = wr1;
            *(uint4*)(wbuf + (wv + 8) * 512 + lane * 8) = wr2;
            *(uint4*)(wbuf + (wv + 12) * 512 + lane * 8) = wr3;
            if (wv < 2)
                *(uint4*)(wbuf + (wv + 16) * 512 + lane * 8) = wr4;
            __syncthreads();
            unsigned short* tp = xcur; xcur = xnxt; xnxt = tp;
        }
    }

    unsigned short* pbw = smem + wv * 3072;   // [w 128][c pad 24] bf16, per-wave
    const int hg = h0 + wv;

    // ---- L (ct0, regs 0..7): bias+relu then reverse cummax over w ----
#pragma unroll
    for (int r = 0; r < 8; ++r) {
        const int m = (r & 3) + 8 * (r >> 2) + 4 * hi1;
        const float shv = shs[m];
        float carry = NEG_INF;
#pragma unroll
        for (int nn = 3; nn >= 0; --nn) {
            float a = fmaxf(acc[0][nn][r] + shv, 0.f);
#pragma unroll
            for (int d = 1; d < 32; d <<= 1) {
                float o = __shfl_down(a, d);
                if (lo5 < 32 - d) a = fmaxf(a, o);
            }
            a = fmaxf(a, carry);
            carry = __shfl(a, hi32);
            acc[0][nn][r] = a;
        }
    }
    // ---- R (ct0, regs 8..15): forward cummax ----
#pragma unroll
    for (int r = 8; r < 16; ++r) {
        const int m = 16 + (r & 3) + 8 * ((r >> 2) & 1) + 4 * hi1;
        const float shv = shs[m];
        float carry = NEG_INF;
#pragma unroll
        for (int nn = 0; nn < 4; ++nn) {
            float a = fmaxf(acc[0][nn][r] + shv, 0.f);
#pragma unroll
            for (int d = 1; d < 32; d <<= 1) {
                float o = __shfl_up(a, d);
                if (lo5 >= d) a = fmaxf(a, o);
            }
            a = fmaxf(a, carry);
            carry = __shfl(a, hi32 | 31);
            acc[0][nn][r] = a;
        }
    }
    // ---- sum L+R -> pbw -> sbuf2 ----
#pragma unroll
    for (int r = 0; r < 8; ++r) {
        const int c16 = (r & 3) + 8 * (r >> 2) + 4 * hi1;
#pragma unroll
        for (int nn = 0; nn < 4; ++nn)
            pbw[(nn * 32 + lo5) * 24 + c16] = f2bf(acc[0][nn][r] + acc[0][nn][r + 8]);
    }
    {
        unsigned short* gdst = sbuf2 + ((size_t)(b * 128 + hg) * 128) * 128 + bx * 16;
#pragma unroll
        for (int i = 0; i < 4; ++i) {    // 256 uint4 segs = 128 w x 16 c
            int idx = lane + i * 64;
            int w = idx >> 1, part = idx & 1;
            *(uint4*)(gdst + (size_t)w * 128 + part * 8) = *(const uint4*)(pbw + w * 24 + part * 8);
        }
    }
    // ---- T (ct1, regs 0..7): bias+relu -> ytbT ----
#pragma unroll
    for (int r = 0; r < 8; ++r) {
        const int c16 = (r & 3) + 8 * (r >> 2) + 4 * hi1;
        const float shv = shs[32 + c16];
#pragma unroll
        for (int nn = 0; nn < 4; ++nn)
            pbw[(nn * 32 + lo5) * 24 + c16] = f2bf(fmaxf(acc[1][nn][r] + shv, 0.f));
    }
    {
        unsigned short* gdst = ytbT + ((size_t)(b * 128 + hg) * 128) * 128 + bx * 16;
#pragma unroll
        for (int i = 0; i < 4; ++i) {
            int idx = lane + i * 64;
            int w = idx >> 1, part = idx & 1;
            *(uint4*)(gdst + (size_t)w * 128 + part * 8) = *(const uint4*)(pbw + w * 24 + part * 8);
        }
    }
    // ---- B (ct1, regs 8..15): bias+relu -> ytbB ----
#pragma unroll
    for (int r = 8; r < 16; ++r) {
        const int c16 = (r & 3) + 8 * ((r >> 2) & 1) + 4 * hi1;
        const float shv = shs[48 + c16];
#pragma unroll
        for (int nn = 0; nn < 4; ++nn)
            pbw[(nn * 32 + lo5) * 24 + c16] = f2bf(fmaxf(acc[1][nn][r] + shv, 0.f));
    }
    {
        unsigned short* gdst = ytbB + ((size_t)(b * 128 + hg) * 128) * 128 + bx * 16;
#pragma unroll
        for (int i = 0; i < 4; ++i) {
            int idx = lane + i * 64;
            int w = idx >> 1, part = idx & 1;
            *(uint4*)(gdst + (size_t)w * 128 + part * 8) = *(const uint4*)(pbw + w * 24 + part * 8);
        }
    }
}

// -------- merged column scans: T (reverse) then B (forward), RMW sbuf2 ----
// r6 REWRITE: barrier-free, LDS-free, vectorized. Each thread owns one
// (w, 8-channel) column chain; in-register cummax walks h serially (the
// scan IS serial in h, but all 16384 (b,w,c8) chains are independent).
// Old version: scalar 2B loads + 64 barrier rounds + LDS bounce.
// Grid (b=8, wx=8): linear id % 8 == b -> XCD j gets batch j (matches
// k_brconv's ytb/sbuf2 write locality). Both passes in one block: T and B
// RMW the same sbuf2 elements -> same thread, no race.
__global__ void __launch_bounds__(256)
k_colscan2(const unsigned short* __restrict__ ytbT, const unsigned short* __restrict__ ytbB,
           unsigned short* __restrict__ sbuf2)
{
    const int t = threadIdx.x;
    const int b = blockIdx.x, wx = blockIdx.y;
    const int w = wx * 16 + (t >> 4), cp = (t & 15) * 8;
    const size_t hs = 128 * 128;                      // h stride (shorts)
    const size_t base = ((size_t)(b * 128) * 128 + w) * 128 + cp;

    // pass 1: reverse cummax over ytbT, add into sbuf2
    {
        float cum[8];
#pragma unroll
        for (int j = 0; j < 8; ++j) cum[j] = NEG_INF;
#pragma unroll 8
        for (int h = 127; h >= 0; --h) {
            uint4 tv = *(const uint4*)(ytbT + base + (size_t)h * hs);
            uint4 sv = *(uint4*)(sbuf2 + base + (size_t)h * hs);
            unsigned short* tp = (unsigned short*)&tv;
            unsigned short* sp = (unsigned short*)&sv;
#pragma unroll
            for (int j = 0; j < 8; ++j) {
                cum[j] = fmaxf(cum[j], bf2f(tp[j]));
                sp[j] = f2bf(bf2f(sp[j]) + cum[j]);
            }
            *(uint4*)(sbuf2 + base + (size_t)h * hs) = sv;
        }
    }
    // pass 2: forward cummax over ytbB, add into sbuf2
    {
        float cum[8];
#pragma unroll
        for (int j = 0; j < 8; ++j) cum[j] = NEG_INF;
#pragma unroll 8
        for (int h = 0; h < 128; ++h) {
            uint4 tv = *(const uint4*)(ytbB + base + (size_t)h * hs);
            uint4 sv = *(uint4*)(sbuf2 + base + (size_t)h * hs);
            unsigned short* tp = (unsigned short*)&tv;
            unsigned short* sp = (unsigned short*)&sv;
#pragma unroll
            for (int j = 0; j < 8; ++j) {
                cum[j] = fmaxf(cum[j], bf2f(tp[j]));
                sp[j] = f2bf(bf2f(sp[j]) + cum[j]);
            }
            *(uint4*)(sbuf2 + base + (size_t)h * hs) = sv;
        }
    }
}

// ---------------- final: conv3x3(sbuf2,128->256) + 1x1(xh) ----------
// 3x3: round-2 structure (wbuf DMA + reg-staged weight prefetch, 2 barriers)
//      + setprio around MFMA (T5, r6).
// 1x1: fully register-direct (staging was an identity rearrangement) --
//      no LDS, no barriers, each byte read exactly once (r4, verified).
// __launch_bounds__(256,2): spill cliff at 3 (r3 lesson).
__global__ void __launch_bounds__(256, 2)
k_final(const unsigned short* __restrict__ sbuf2, const unsigned short* __restrict__ xh,
        const unsigned short* __restrict__ wpk2, const unsigned short* __restrict__ wpk1,
        const float* __restrict__ obF, float* __restrict__ out)
{
    __shared__ __align__(16) unsigned short smem[2 * XIN_SH + WBUF_SH + 128];
    unsigned short* xinA = smem;
    unsigned short* xinB = smem + XIN_SH;
    unsigned short* wbuf = smem + 2 * XIN_SH;
    float* obs = (float*)(smem + 2 * XIN_SH + WBUF_SH);

    const int t = threadIdx.x;
    // XCD swizzle (nwg=1024): XCD j works batch b=j
    const int lin = (int)blockIdx.x + ((int)blockIdx.y << 2) + ((int)blockIdx.z << 7);
    const int swz = (lin & 7) * 128 + (lin >> 3);
    const int bx = swz & 3, h0 = ((swz >> 2) & 31) << 2, b = swz >> 7;
    const int wv = t >> 6, lane = t & 63;
    const int lo5 = lane & 31, hi1 = lane >> 5;

    if (t < 64) obs[t] = obF[bx * 64 + t];
    for (int idx = t; idx < 3168; idx += 256)
        *(uint4*)(smem + idx * 8) = make_uint4(0, 0, 0, 0);

    f32x16 acc[2][4];
#pragma unroll
    for (int ct = 0; ct < 2; ++ct)
#pragma unroll
        for (int nb = 0; nb < 4; ++nb)
#pragma unroll
            for (int i = 0; i < 16; ++i) acc[ct][nb][i] = 0.f;

    __syncthreads();

    // ---- prologue: stage 3x3 chunk 0 (xin + weights) ----
    for (int s = wv; s < 24; s += 4) {
        int r = s >> 2, khi = (s >> 1) & 1, half = s & 1;
        int ih = h0 - 1 + r;
        if (ih >= 0 && ih < 128)
            gl_lds(sbuf2 + (((size_t)(b * 128 + ih) * 128 + half * 64 + lane) * 128) + khi * 8,
                   xinA + ((r * 2 + khi) * 132 + 1 + half * 64) * 8, lane);
    }
    for (int s = wv; s < 18; s += 4)
        gl_lds(wpk2 + ((size_t)s * 256 + bx * 64 + lane) * 8, wbuf + s * 512, lane);
    __syncthreads();

    uint4 wr0 = make_uint4(0, 0, 0, 0), wr1 = wr0, wr2 = wr0, wr3 = wr0, wr4 = wr0;
    unsigned short* xcur = xinA;
    unsigned short* xnxt = xinB;

    // ---- 3x3 over sbuf2: 8 ci-chunks, 2-phase ----
    for (int cb = 0; cb < 8; ++cb) {
        if (cb < 7) {
            const int nc = cb + 1;
            for (int s = wv; s < 24; s += 4) {
                int r = s >> 2, khi = (s >> 1) & 1, half = s & 1;
                int ih = h0 - 1 + r;
                if (ih >= 0 && ih < 128)
                    gl_lds(sbuf2 + (((size_t)(b * 128 + ih) * 128 + half * 64 + lane) * 128) + nc * 16 + khi * 8,
                           xnxt + ((r * 2 + khi) * 132 + 1 + half * 64) * 8, lane);
            }
            wr0 = *(const uint4*)(wpk2 + ((size_t)(nc * 18 + wv) * 256 + bx * 64 + lane) * 8);
            wr1 = *(const uint4*)(wpk2 + ((size_t)(nc * 18 + wv + 4) * 256 + bx * 64 + lane) * 8);
            wr2 = *(const uint4*)(wpk2 + ((size_t)(nc * 18 + wv + 8) * 256 + bx * 64 + lane) * 8);
            wr3 = *(const uint4*)(wpk2 + ((size_t)(nc * 18 + wv + 12) * 256 + bx * 64 + lane) * 8);
            if (wv < 2)
                wr4 = *(const uint4*)(wpk2 + ((size_t)(nc * 18 + wv + 16) * 256 + bx * 64 + lane) * 8);
        }
        __builtin_amdgcn_s_setprio(1);
#pragma unroll
        for (int k9 = 0; k9 < 9; ++k9) {
            const int kh = k9 / 3, kw = k9 % 3;
            bf16x8 a0 = *(const bf16x8*)(wbuf + ((k9 * 2 + hi1) * 64 + lo5) * 8);
            bf16x8 a1 = *(const bf16x8*)(wbuf + ((k9 * 2 + hi1) * 64 + 32 + lo5) * 8);
#pragma unroll
            for (int nb = 0; nb < 4; ++nb) {
                bf16x8 bf = *(const bf16x8*)(xcur + (((wv + kh) * 2 + hi1) * 132 + nb * 32 + lo5 + kw) * 8);
                acc[0][nb] = __builtin_amdgcn_mfma_f32_32x32x16_bf16(a0, bf, acc[0][nb], 0, 0, 0);
                acc[1][nb] = __builtin_amdgcn_mfma_f32_32x32x16_bf16(a1, bf, acc[1][nb], 0, 0, 0);
            }
        }
        __builtin_amdgcn_s_setprio(0);
        __syncthreads();
        if (cb < 7) {
            *(uint4*)(wbuf + (wv) * 512 + lane * 8) = wr0;
            *(uint4*)(wbuf + (wv + 4) * 512 + lane * 8) = wr1;
            *(uint4*)(wbuf + (wv + 8) * 512 + lane * 8) = wr2;
            *(uint4*)(wbuf + (wv + 12) * 512 + lane * 8) = wr3;
            if (wv < 2)
                *(uint4*)(wbuf + (wv + 16) * 512 + lane * 8) = wr4;
            __syncthreads();
            unsigned short* tp = xcur; xcur = xnxt; xnxt = tp;
        }
    }

    // ---- 1x1 over xh: direct global->reg, no LDS, no barriers ----
    {
        const unsigned short* xrow = xh + ((size_t)(b * 128 + h0 + wv) * 128) * 256 + hi1 * 8;
        const unsigned short* w1p  = wpk1 + ((size_t)hi1 * 256 + bx * 64) * 8;
#pragma unroll 4
        for (int cb = 0; cb < 16; ++cb) {
            bf16x8 a0 = *(const bf16x8*)(w1p + ((size_t)cb * 512 + lo5) * 8);
            bf16x8 a1 = *(const bf16x8*)(w1p + ((size_t)cb * 512 + 32 + lo5) * 8);
#pragma unroll
            for (int nb = 0; nb < 4; ++nb) {
                bf16x8 bf = *(const bf16x8*)(xrow + (size_t)(nb * 32 + lo5) * 256 + cb * 16);
                acc[0][nb] = __builtin_amdgcn_mfma_f32_32x32x16_bf16(a0, bf, acc[0][nb], 0, 0, 0);
                acc[1][nb] = __builtin_amdgcn_mfma_f32_32x32x16_bf16(a1, bf, acc[1][nb], 0, 0, 0);
            }
        }
    }

    // epilogue: bias + relu, fp32 NCHW stores (coalesced 32-lane segments)
    const int hg = h0 + wv;
#pragma unroll
    for (int ct = 0; ct < 2; ++ct)
#pragma unroll
        for (int r = 0; r < 16; ++r) {
            const int m = ct * 32 + (r & 3) + 8 * (r >> 2) + 4 * hi1;
            const float bias = obs[m];
#pragma unroll
            for (int nb = 0; nb < 4; ++nb)
                out[((size_t)(b * 256 + bx * 64 + m) * 128 + hg) * 128 + nb * 32 + lo5] =
                    fmaxf(acc[ct][nb][r] + bias, 0.f);
        }
}

extern "C" void kernel_launch(void* const* d_in, const int* in_sizes, int n_in,
                              void* d_out, int out_size, void* d_ws, size_t ws_size,
                              hipStream_t stream)
{
    const float* x   = (const float*)d_in[0];
    const float* w_l = (const float*)d_in[1];
    const float* s_l = (const float*)d_in[2];
    const float* o_l = (const float*)d_in[3];
    const float* w_r = (const float*)d_in[4];
    const float* s_r = (const float*)d_in[5];
    const float* o_r = (const float*)d_in[6];
    const float* w_t = (const float*)d_in[7];
    const float* s_t = (const float*)d_in[8];
    const float* o_t = (const float*)d_in[9];
    const float* w_b = (const float*)d_in[10];
    const float* s_b = (const float*)d_in[11];
    const float* o_b = (const float*)d_in[12];
    const float* w2  = (const float*)d_in[13];
    const float* s2  = (const float*)d_in[14];
    const float* o2  = (const float*)d_in[15];
    const float* w1  = (const float*)d_in[16];
    const float* s1  = (const float*)d_in[17];
    const float* o1  = (const float*)d_in[18];
    float* out = (float*)d_out;
    char*  ws  = (char*)d_ws;

    unsigned short* xh    = (unsigned short*)(ws + 0);            // 64 MiB
    unsigned short* sbuf2 = (unsigned short*)(ws + 67108864);     // 32 MiB
    unsigned short* wpkBR = (unsigned short*)(ws + 100663296);    // 2.25 MiB
    unsigned short* wpk2  = (unsigned short*)(ws + 103022592);    // 576 KiB
    unsigned short* wpk1  = (unsigned short*)(ws + 103612416);    // 128 KiB
    float* shF = (float*)(ws + 103743488);
    float* obF = (float*)(ws + 103745536);

    unsigned short* ytbT = (unsigned short*)d_out;   // d_out as scratch (bf16, 2x32MiB)
    unsigned short* ytbB = ytbT + 16777216;

    dim3 blk(256);
    k_xpose<<<dim3(4, 128, 8), blk, 0, stream>>>(x, xh);
    k_wpack<<<dim3(6019), blk, 0, stream>>>(w_l, s_l, o_l, w_r, s_r, o_r,
                                            w_t, s_t, o_t, w_b, s_b, o_b,
                                            w2, s2, o2, w1, s1, o1,
                                            wpkBR, wpk2, wpk1, shF, obF);
    k_brconv<<<dim3(8, 32, 8), blk, 0, stream>>>(xh, wpkBR, shF, sbuf2, ytbT, ytbB);
    k_colscan2<<<dim3(8, 8), blk, 0, stream>>>(ytbT, ytbB, sbuf2);
    k_final<<<dim3(4, 32, 8), blk, 0, stream>>>(sbuf2, xh, wpk2, wpk1, obF, out);
}

// Round 7
// 677.619 us; speedup vs baseline: 1.2054x; 1.2054x over previous
//
#include <hip/hip_runtime.h>

#define NEG_INF (-3.402823466e+38f)

typedef __bf16 bf16x8 __attribute__((ext_vector_type(8)));
typedef float  f32x16 __attribute__((ext_vector_type(16)));

__device__ __forceinline__ unsigned short f2bf(float f){
    unsigned u = __builtin_bit_cast(unsigned, f);
    u += 0x7fffu + ((u >> 16) & 1u);
    return (unsigned short)(u >> 16);
}
__device__ __forceinline__ float bf2f(unsigned short h){
    unsigned u = ((unsigned)h) << 16;
    return __builtin_bit_cast(float, u);
}

#if defined(__has_builtin)
#if __has_builtin(__builtin_amdgcn_global_load_lds)
#define ASYNC_CP 1
#endif
#endif

// async global->LDS: per-lane g, wave-uniform lbase; lane i lands at lbase + i*16B
__device__ __forceinline__ void gl_lds(const unsigned short* g, unsigned short* lbase, int lane) {
#ifdef ASYNC_CP
    __builtin_amdgcn_global_load_lds(
        (const __attribute__((address_space(1))) unsigned int*)g,
        (__attribute__((address_space(3))) unsigned int*)lbase, 16, 0, 0);
#else
    *(uint4*)(lbase + (size_t)lane * 8) = *(const uint4*)g;
#endif
}

// ---------------- prep: x fp32 NCHW -> bf16 NHWC -------------------
__global__ void __launch_bounds__(256)
k_xpose(const float* __restrict__ x, unsigned short* __restrict__ xh)
{
    __shared__ float tile[64 * 129];
    const int t = threadIdx.x;
    const int ci0 = blockIdx.x * 64, h = blockIdx.y, b = blockIdx.z;
    const float4* src = (const float4*)x;
#pragma unroll
    for (int i = 0; i < 8; ++i) {
        int idx = t + i * 256;
        int ci = idx >> 5, w4 = idx & 31;
        float4 v = src[((b * 256 + ci0 + ci) * 128 + h) * 32 + w4];
        tile[ci * 129 + w4 * 4 + 0] = v.x;
        tile[ci * 129 + w4 * 4 + 1] = v.y;
        tile[ci * 129 + w4 * 4 + 2] = v.z;
        tile[ci * 129 + w4 * 4 + 3] = v.w;
    }
    __syncthreads();
    unsigned* dst = (unsigned*)xh;
#pragma unroll
    for (int i = 0; i < 16; ++i) {
        int idx = t + i * 256;
        int w = idx >> 5, cp = idx & 31;
        float lo = tile[(cp * 2 + 0) * 129 + w];
        float hi = tile[(cp * 2 + 1) * 129 + w];
        dst[((b * 128 + h) * 128 + w) * 128 + (ci0 >> 1) + cp] =
            (unsigned)f2bf(lo) | ((unsigned)f2bf(hi) << 16);
    }
}

// ---------------- prep: weight packing (BN scale folded) -----------
__global__ void __launch_bounds__(256)
k_wpack(const float* __restrict__ wl, const float* __restrict__ sl, const float* __restrict__ ol,
        const float* __restrict__ wr, const float* __restrict__ sr, const float* __restrict__ orr,
        const float* __restrict__ wt, const float* __restrict__ st, const float* __restrict__ ot,
        const float* __restrict__ wb, const float* __restrict__ sb, const float* __restrict__ ob,
        const float* __restrict__ w2, const float* __restrict__ s2, const float* __restrict__ o2,
        const float* __restrict__ w1, const float* __restrict__ s1, const float* __restrict__ o1,
        unsigned short* __restrict__ wpkBR, unsigned short* __restrict__ wpk2,
        unsigned short* __restrict__ wpk1, float* __restrict__ shF, float* __restrict__ obF)
{
    int i = blockIdx.x * 256 + threadIdx.x;
    if (i < 1179648) {
        int br = i / 294912, r = i % 294912;
        int c = r / 2304, r2 = r % 2304, ci = r2 / 9, k9 = r2 % 9;
        const float* wp = br == 0 ? wl : br == 1 ? wr : br == 2 ? wt : wb;
        const float* sp = br == 0 ? sl : br == 1 ? sr : br == 2 ? st : sb;
        float v = wp[r] * sp[c];
        int p = (c >> 4) * 64 + br * 16 + (c & 15);
        wpkBR[(((((ci >> 4) * 9 + k9) * 2 + ((ci >> 3) & 1)) * 512 + p) * 8) + (ci & 7)] = f2bf(v);
    } else if (i < 1474560) {
        int j = i - 1179648;
        int c = j / 1152, r2 = j % 1152, ci = r2 / 9, k9 = r2 % 9;
        wpk2[(((((ci >> 4) * 9 + k9) * 2 + ((ci >> 3) & 1)) * 256 + c) * 8) + (ci & 7)] = f2bf(w2[j] * s2[c]);
    } else if (i < 1540096) {
        int j = i - 1474560;
        int c = j >> 8, ci = j & 255;
        wpk1[((((ci >> 4) * 2 + ((ci >> 3) & 1)) * 256 + c) * 8) + (ci & 7)] = f2bf(w1[j] * s1[c]);
    } else if (i < 1540608) {
        int p = i - 1540096;
        int br = (p >> 4) & 3, c = (p >> 6) * 16 + (p & 15);
        const float* op = br == 0 ? ol : br == 1 ? orr : br == 2 ? ot : ob;
        shF[p] = op[c];
    } else if (i < 1540864) {
        int c = i - 1540608;
        obF[c] = o2[c] + o1[c];
    }
}

// ---------------- branch conv: all 4 branches, 4 rows/block --------
// ROUND-2 STRUCTURE (measured 310-312us, MfmaUtil 47-48%): xin double-
// buffered (gl_lds 2-phase prefetch), weights DMA'd to LDS wbuf once per
// chunk, broadcast to all 4 waves; next chunk's weights reg-staged during
// compute, written to wbuf between the two barriers.
// A/B: direct global->reg A-frags = 347us (r4, L1 thrash). Keep wbuf.
// A/B: setprio around MFMA = neutral (r6: 310.4 vs r5: 309.9). Kept.
// __launch_bounds__(256,2): (256,3) caps regs at 170 -> acc spills ->
// 2.7GB scratch, 3.3x slower (r3 lesson). Do NOT raise.
#define XIN_SH 12672
#define WBUF_SH 9216
__global__ void __launch_bounds__(256, 2)
k_brconv(const unsigned short* __restrict__ xh, const unsigned short* __restrict__ wpkBR,
         const float* __restrict__ shF, unsigned short* __restrict__ sbuf2,
         unsigned short* __restrict__ ytbT, unsigned short* __restrict__ ytbB)
{
    __shared__ __align__(16) unsigned short smem[2 * XIN_SH + WBUF_SH + 128];
    unsigned short* xinA = smem;
    unsigned short* xinB = smem + XIN_SH;
    unsigned short* wbuf = smem + 2 * XIN_SH;
    float* shs = (float*)(smem + 2 * XIN_SH + WBUF_SH);

    const int t = threadIdx.x;
    // XCD-aware bijective swizzle (nwg=2048): XCD j works batch b=j; co-resident
    // blocks on one XCD share xin strips + all weight slices in L2.
    const int lin = (int)blockIdx.x + ((int)blockIdx.y << 3) + ((int)blockIdx.z << 8);
    const int swz = (lin & 7) * 256 + (lin >> 3);
    const int bx = swz & 7, h0 = ((swz >> 3) & 31) << 2, b = swz >> 8;
    const int wv = t >> 6, lane = t & 63;
    const int lo5 = lane & 31, hi1 = lane >> 5;
    const int hi32 = lane & 32;

    if (t < 64) shs[t] = shF[bx * 64 + t];
    // zero BOTH xin buffers once: halo cols + OOB rows stay zero forever
    for (int idx = t; idx < 3168; idx += 256)
        *(uint4*)(smem + idx * 8) = make_uint4(0, 0, 0, 0);

    f32x16 acc[2][4];
#pragma unroll
    for (int ct = 0; ct < 2; ++ct)
#pragma unroll
        for (int nb = 0; nb < 4; ++nb)
#pragma unroll
            for (int i = 0; i < 16; ++i) acc[ct][nb][i] = 0.f;

    __syncthreads();   // zero-init visible before async stores land

    // ---- prologue: stage chunk 0 (xin + weights via gl_lds) ----
    for (int s = wv; s < 24; s += 4) {
        int r = s >> 2, khi = (s >> 1) & 1, half = s & 1;
        int ih = h0 - 1 + r;
        if (ih >= 0 && ih < 128)
            gl_lds(xh + (((size_t)(b * 128 + ih) * 128 + half * 64 + lane) * 256) + khi * 8,
                   xinA + ((r * 2 + khi) * 132 + 1 + half * 64) * 8, lane);
    }
    for (int s = wv; s < 18; s += 4)
        gl_lds(wpkBR + ((size_t)s * 512 + bx * 64 + lane) * 8, wbuf + s * 512, lane);
    __syncthreads();

    uint4 wr0 = make_uint4(0, 0, 0, 0), wr1 = wr0, wr2 = wr0, wr3 = wr0, wr4 = wr0;
    unsigned short* xcur = xinA;
    unsigned short* xnxt = xinB;

    for (int cb = 0; cb < 16; ++cb) {
        // issue next-chunk staging BEFORE compute -> overlaps with MFMA phase
        if (cb < 15) {
            const int nc = cb + 1;
            for (int s = wv; s < 24; s += 4) {
                int r = s >> 2, khi = (s >> 1) & 1, half = s & 1;
                int ih = h0 - 1 + r;
                if (ih >= 0 && ih < 128)
                    gl_lds(xh + (((size_t)(b * 128 + ih) * 128 + half * 64 + lane) * 256) + nc * 16 + khi * 8,
                           xnxt + ((r * 2 + khi) * 132 + 1 + half * 64) * 8, lane);
            }
            wr0 = *(const uint4*)(wpkBR + ((size_t)(nc * 18 + wv) * 512 + bx * 64 + lane) * 8);
            wr1 = *(const uint4*)(wpkBR + ((size_t)(nc * 18 + wv + 4) * 512 + bx * 64 + lane) * 8);
            wr2 = *(const uint4*)(wpkBR + ((size_t)(nc * 18 + wv + 8) * 512 + bx * 64 + lane) * 8);
            wr3 = *(const uint4*)(wpkBR + ((size_t)(nc * 18 + wv + 12) * 512 + bx * 64 + lane) * 8);
            if (wv < 2)
                wr4 = *(const uint4*)(wpkBR + ((size_t)(nc * 18 + wv + 16) * 512 + bx * 64 + lane) * 8);
        }
        __builtin_amdgcn_s_setprio(1);
#pragma unroll
        for (int k9 = 0; k9 < 9; ++k9) {
            const int kh = k9 / 3, kw = k9 % 3;
            bf16x8 a0 = *(const bf16x8*)(wbuf + ((k9 * 2 + hi1) * 64 + lo5) * 8);
            bf16x8 a1 = *(const bf16x8*)(wbuf + ((k9 * 2 + hi1) * 64 + 32 + lo5) * 8);
#pragma unroll
            for (int nb = 0; nb < 4; ++nb) {
                bf16x8 bf = *(const bf16x8*)(xcur + (((wv + kh) * 2 + hi1) * 132 + nb * 32 + lo5 + kw) * 8);
                acc[0][nb] = __builtin_amdgcn_mfma_f32_32x32x16_bf16(a0, bf, acc[0][nb], 0, 0, 0);
                acc[1][nb] = __builtin_amdgcn_mfma_f32_32x32x16_bf16(a1, bf, acc[1][nb], 0, 0, 0);
            }
        }
        __builtin_amdgcn_s_setprio(0);
        __syncthreads();   // drains overlapped vmcnt; all waves done reading wbuf
        if (cb < 15) {
            *(uint4*)(wbuf + (wv) * 512 + lane * 8) = wr0;
            *(uint4*)(wbuf + (wv + 4) * 512 + lane * 8) = wr1;
            *(uint4*)(wbuf + (wv + 8) * 512 + lane * 8) = wr2;
            *(uint4*)(wbuf + (wv + 12) * 512 + lane * 8) = wr3;
            if (wv < 2)
                *(uint4*)(wbuf + (wv + 16) * 512 + lane * 8) = wr4;
            __syncthreads();
            unsigned short* tp = xcur; xcur = xnxt; xnxt = tp;
        }
    }

    unsigned short* pbw = smem + wv * 3072;   // [w 128][c pad 24] bf16, per-wave
    const int hg = h0 + wv;

    // ---- L (ct0, regs 0..7): bias+relu then reverse cummax over w ----
#pragma unroll
    for (int r = 0; r < 8; ++r) {
        const int m = (r & 3) + 8 * (r >> 2) + 4 * hi1;
        const float shv = shs[m];
        float carry = NEG_INF;
#pragma unroll
        for (int nn = 3; nn >= 0; --nn) {
            float a = fmaxf(acc[0][nn][r] + shv, 0.f);
#pragma unroll
            for (int d = 1; d < 32; d <<= 1) {
                float o = __shfl_down(a, d);
                if (lo5 < 32 - d) a = fmaxf(a, o);
            }
            a = fmaxf(a, carry);
            carry = __shfl(a, hi32);
            acc[0][nn][r] = a;
        }
    }
    // ---- R (ct0, regs 8..15): forward cummax ----
#pragma unroll
    for (int r = 8; r < 16; ++r) {
        const int m = 16 + (r & 3) + 8 * ((r >> 2) & 1) + 4 * hi1;
        const float shv = shs[m];
        float carry = NEG_INF;
#pragma unroll
        for (int nn = 0; nn < 4; ++nn) {
            float a = fmaxf(acc[0][nn][r] + shv, 0.f);
#pragma unroll
            for (int d = 1; d < 32; d <<= 1) {
                float o = __shfl_up(a, d);
                if (lo5 >= d) a = fmaxf(a, o);
            }
            a = fmaxf(a, carry);
            carry = __shfl(a, hi32 | 31);
            acc[0][nn][r] = a;
        }
    }
    // ---- sum L+R -> pbw -> sbuf2 ----
#pragma unroll
    for (int r = 0; r < 8; ++r) {
        const int c16 = (r & 3) + 8 * (r >> 2) + 4 * hi1;
#pragma unroll
        for (int nn = 0; nn < 4; ++nn)
            pbw[(nn * 32 + lo5) * 24 + c16] = f2bf(acc[0][nn][r] + acc[0][nn][r + 8]);
    }
    {
        unsigned short* gdst = sbuf2 + ((size_t)(b * 128 + hg) * 128) * 128 + bx * 16;
#pragma unroll
        for (int i = 0; i < 4; ++i) {    // 256 uint4 segs = 128 w x 16 c
            int idx = lane + i * 64;
            int w = idx >> 1, part = idx & 1;
            *(uint4*)(gdst + (size_t)w * 128 + part * 8) = *(const uint4*)(pbw + w * 24 + part * 8);
        }
    }
    // ---- T (ct1, regs 0..7): bias+relu -> ytbT ----
#pragma unroll
    for (int r = 0; r < 8; ++r) {
        const int c16 = (r & 3) + 8 * (r >> 2) + 4 * hi1;
        const float shv = shs[32 + c16];
#pragma unroll
        for (int nn = 0; nn < 4; ++nn)
            pbw[(nn * 32 + lo5) * 24 + c16] = f2bf(fmaxf(acc[1][nn][r] + shv, 0.f));
    }
    {
        unsigned short* gdst = ytbT + ((size_t)(b * 128 + hg) * 128) * 128 + bx * 16;
#pragma unroll
        for (int i = 0; i < 4; ++i) {
            int idx = lane + i * 64;
            int w = idx >> 1, part = idx & 1;
            *(uint4*)(gdst + (size_t)w * 128 + part * 8) = *(const uint4*)(pbw + w * 24 + part * 8);
        }
    }
    // ---- B (ct1, regs 8..15): bias+relu -> ytbB ----
#pragma unroll
    for (int r = 8; r < 16; ++r) {
        const int c16 = (r & 3) + 8 * ((r >> 2) & 1) + 4 * hi1;
        const float shv = shs[48 + c16];
#pragma unroll
        for (int nn = 0; nn < 4; ++nn)
            pbw[(nn * 32 + lo5) * 24 + c16] = f2bf(fmaxf(acc[1][nn][r] + shv, 0.f));
    }
    {
        unsigned short* gdst = ytbB + ((size_t)(b * 128 + hg) * 128) * 128 + bx * 16;
#pragma unroll
        for (int i = 0; i < 4; ++i) {
            int idx = lane + i * 64;
            int w = idx >> 1, part = idx & 1;
            *(uint4*)(gdst + (size_t)w * 128 + part * 8) = *(const uint4*)(pbw + w * 24 + part * 8);
        }
    }
}

// -------- merged column scans: T (reverse) then B (forward), RMW sbuf2 ----
// r7: chain scan, occupancy FIXED. r6's uint4 chains gave only 64 blocks
// (16384 chains / 256 thr) -> 75% of CUs idle -> +135us regression.
// Now uint (2-channel) chains: 65536 chains -> 256 blocks, every CU busy,
// 4 waves/CU. Wave's 64 lanes cover one w's 128 channels = 256B/inst
// contiguous. unroll 8 keeps ~16 independent loads in flight per lane.
// Floor: 256MB traffic ~= 41us at 6.3TB/s.
// Grid (b=8, wx=32): lin%8==b -> XCD j gets batch j (matches brconv).
__global__ void __launch_bounds__(256)
k_colscan2(const unsigned short* __restrict__ ytbT, const unsigned short* __restrict__ ytbB,
           unsigned short* __restrict__ sbuf2)
{
    const int t = threadIdx.x;
    const int b = blockIdx.x, wx = blockIdx.y;
    const int w = wx * 4 + (t >> 6), cp = (t & 63) * 2;
    const size_t hs = 128 * 128;                      // h stride (shorts)
    const size_t base = ((size_t)(b * 128) * 128 + w) * 128 + cp;

    // pass 1: reverse cummax over ytbT, add into sbuf2
    {
        float c0 = NEG_INF, c1 = NEG_INF;
#pragma unroll 8
        for (int h = 127; h >= 0; --h) {
            unsigned tv = *(const unsigned*)(ytbT + base + (size_t)h * hs);
            unsigned sv = *(const unsigned*)(sbuf2 + base + (size_t)h * hs);
            c0 = fmaxf(c0, bf2f((unsigned short)(tv & 0xffffu)));
            c1 = fmaxf(c1, bf2f((unsigned short)(tv >> 16)));
            unsigned r = (unsigned)f2bf(bf2f((unsigned short)(sv & 0xffffu)) + c0)
                       | ((unsigned)f2bf(bf2f((unsigned short)(sv >> 16)) + c1) << 16);
            *(unsigned*)(sbuf2 + base + (size_t)h * hs) = r;
        }
    }
    // pass 2: forward cummax over ytbB, add into sbuf2
    {
        float c0 = NEG_INF, c1 = NEG_INF;
#pragma unroll 8
        for (int h = 0; h < 128; ++h) {
            unsigned tv = *(const unsigned*)(ytbB + base + (size_t)h * hs);
            unsigned sv = *(const unsigned*)(sbuf2 + base + (size_t)h * hs);
            c0 = fmaxf(c0, bf2f((unsigned short)(tv & 0xffffu)));
            c1 = fmaxf(c1, bf2f((unsigned short)(tv >> 16)));
            unsigned r = (unsigned)f2bf(bf2f((unsigned short)(sv & 0xffffu)) + c0)
                       | ((unsigned)f2bf(bf2f((unsigned short)(sv >> 16)) + c1) << 16);
            *(unsigned*)(sbuf2 + base + (size_t)h * hs) = r;
        }
    }
}

// ---------------- final: conv3x3(sbuf2,128->256) + 1x1(xh) ----------
// 3x3: round-2 structure (wbuf DMA + reg-staged weight prefetch, 2 barriers)
//      + setprio around MFMA (neutral A/B, kept).
// 1x1: fully register-direct (staging was an identity rearrangement) --
//      no LDS, no barriers, each byte read exactly once (r4, verified).
// __launch_bounds__(256,2): spill cliff at 3 (r3 lesson).
__global__ void __launch_bounds__(256, 2)
k_final(const unsigned short* __restrict__ sbuf2, const unsigned short* __restrict__ xh,
        const unsigned short* __restrict__ wpk2, const unsigned short* __restrict__ wpk1,
        const float* __restrict__ obF, float* __restrict__ out)
{
    __shared__ __align__(16) unsigned short smem[2 * XIN_SH + WBUF_SH + 128];
    unsigned short* xinA = smem;
    unsigned short* xinB = smem + XIN_SH;
    unsigned short* wbuf = smem + 2 * XIN_SH;
    float* obs = (float*)(smem + 2 * XIN_SH + WBUF_SH);

    const int t = threadIdx.x;
    // XCD swizzle (nwg=1024): XCD j works batch b=j
    const int lin = (int)blockIdx.x + ((int)blockIdx.y << 2) + ((int)blockIdx.z << 7);
    const int swz = (lin & 7) * 128 + (lin >> 3);
    const int bx = swz & 3, h0 = ((swz >> 2) & 31) << 2, b = swz >> 7;
    const int wv = t >> 6, lane = t & 63;
    const int lo5 = lane & 31, hi1 = lane >> 5;

    if (t < 64) obs[t] = obF[bx * 64 + t];
    for (int idx = t; idx < 3168; idx += 256)
        *(uint4*)(smem + idx * 8) = make_uint4(0, 0, 0, 0);

    f32x16 acc[2][4];
#pragma unroll
    for (int ct = 0; ct < 2; ++ct)
#pragma unroll
        for (int nb = 0; nb < 4; ++nb)
#pragma unroll
            for (int i = 0; i < 16; ++i) acc[ct][nb][i] = 0.f;

    __syncthreads();

    // ---- prologue: stage 3x3 chunk 0 (xin + weights) ----
    for (int s = wv; s < 24; s += 4) {
        int r = s >> 2, khi = (s >> 1) & 1, half = s & 1;
        int ih = h0 - 1 + r;
        if (ih >= 0 && ih < 128)
            gl_lds(sbuf2 + (((size_t)(b * 128 + ih) * 128 + half * 64 + lane) * 128) + khi * 8,
                   xinA + ((r * 2 + khi) * 132 + 1 + half * 64) * 8, lane);
    }
    for (int s = wv; s < 18; s += 4)
        gl_lds(wpk2 + ((size_t)s * 256 + bx * 64 + lane) * 8, wbuf + s * 512, lane);
    __syncthreads();

    uint4 wr0 = make_uint4(0, 0, 0, 0), wr1 = wr0, wr2 = wr0, wr3 = wr0, wr4 = wr0;
    unsigned short* xcur = xinA;
    unsigned short* xnxt = xinB;

    // ---- 3x3 over sbuf2: 8 ci-chunks, 2-phase ----
    for (int cb = 0; cb < 8; ++cb) {
        if (cb < 7) {
            const int nc = cb + 1;
            for (int s = wv; s < 24; s += 4) {
                int r = s >> 2, khi = (s >> 1) & 1, half = s & 1;
                int ih = h0 - 1 + r;
                if (ih >= 0 && ih < 128)
                    gl_lds(sbuf2 + (((size_t)(b * 128 + ih) * 128 + half * 64 + lane) * 128) + nc * 16 + khi * 8,
                           xnxt + ((r * 2 + khi) * 132 + 1 + half * 64) * 8, lane);
            }
            wr0 = *(const uint4*)(wpk2 + ((size_t)(nc * 18 + wv) * 256 + bx * 64 + lane) * 8);
            wr1 = *(const uint4*)(wpk2 + ((size_t)(nc * 18 + wv + 4) * 256 + bx * 64 + lane) * 8);
            wr2 = *(const uint4*)(wpk2 + ((size_t)(nc * 18 + wv + 8) * 256 + bx * 64 + lane) * 8);
            wr3 = *(const uint4*)(wpk2 + ((size_t)(nc * 18 + wv + 12) * 256 + bx * 64 + lane) * 8);
            if (wv < 2)
                wr4 = *(const uint4*)(wpk2 + ((size_t)(nc * 18 + wv + 16) * 256 + bx * 64 + lane) * 8);
        }
        __builtin_amdgcn_s_setprio(1);
#pragma unroll
        for (int k9 = 0; k9 < 9; ++k9) {
            const int kh = k9 / 3, kw = k9 % 3;
            bf16x8 a0 = *(const bf16x8*)(wbuf + ((k9 * 2 + hi1) * 64 + lo5) * 8);
            bf16x8 a1 = *(const bf16x8*)(wbuf + ((k9 * 2 + hi1) * 64 + 32 + lo5) * 8);
#pragma unroll
            for (int nb = 0; nb < 4; ++nb) {
                bf16x8 bf = *(const bf16x8*)(xcur + (((wv + kh) * 2 + hi1) * 132 + nb * 32 + lo5 + kw) * 8);
                acc[0][nb] = __builtin_amdgcn_mfma_f32_32x32x16_bf16(a0, bf, acc[0][nb], 0, 0, 0);
                acc[1][nb] = __builtin_amdgcn_mfma_f32_32x32x16_bf16(a1, bf, acc[1][nb], 0, 0, 0);
            }
        }
        __builtin_amdgcn_s_setprio(0);
        __syncthreads();
        if (cb < 7) {
            *(uint4*)(wbuf + (wv) * 512 + lane * 8) = wr0;
            *(uint4*)(wbuf + (wv + 4) * 512 + lane * 8) = wr1;
            *(uint4*)(wbuf + (wv + 8) * 512 + lane * 8) = wr2;
            *(uint4*)(wbuf + (wv + 12) * 512 + lane * 8) = wr3;
            if (wv < 2)
                *(uint4*)(wbuf + (wv + 16) * 512 + lane * 8) = wr4;
            __syncthreads();
            unsigned short* tp = xcur; xcur = xnxt; xnxt = tp;
        }
    }

    // ---- 1x1 over xh: direct global->reg, no LDS, no barriers ----
    {
        const unsigned short* xrow = xh + ((size_t)(b * 128 + h0 + wv) * 128) * 256 + hi1 * 8;
        const unsigned short* w1p  = wpk1 + ((size_t)hi1 * 256 + bx * 64) * 8;
#pragma unroll 4
        for (int cb = 0; cb < 16; ++cb) {
            bf16x8 a0 = *(const bf16x8*)(w1p + ((size_t)cb * 512 + lo5) * 8);
            bf16x8 a1 = *(const bf16x8*)(w1p + ((size_t)cb * 512 + 32 + lo5) * 8);
#pragma unroll
            for (int nb = 0; nb < 4; ++nb) {
                bf16x8 bf = *(const bf16x8*)(xrow + (size_t)(nb * 32 + lo5) * 256 + cb * 16);
                acc[0][nb] = __builtin_amdgcn_mfma_f32_32x32x16_bf16(a0, bf, acc[0][nb], 0, 0, 0);
                acc[1][nb] = __builtin_amdgcn_mfma_f32_32x32x16_bf16(a1, bf, acc[1][nb], 0, 0, 0);
            }
        }
    }

    // epilogue: bias + relu, fp32 NCHW stores (coalesced 32-lane segments)
    const int hg = h0 + wv;
#pragma unroll
    for (int ct = 0; ct < 2; ++ct)
#pragma unroll
        for (int r = 0; r < 16; ++r) {
            const int m = ct * 32 + (r & 3) + 8 * (r >> 2) + 4 * hi1;
            const float bias = obs[m];
#pragma unroll
            for (int nb = 0; nb < 4; ++nb)
                out[((size_t)(b * 256 + bx * 64 + m) * 128 + hg) * 128 + nb * 32 + lo5] =
                    fmaxf(acc[ct][nb][r] + bias, 0.f);
        }
}

extern "C" void kernel_launch(void* const* d_in, const int* in_sizes, int n_in,
                              void* d_out, int out_size, void* d_ws, size_t ws_size,
                              hipStream_t stream)
{
    const float* x   = (const float*)d_in[0];
    const float* w_l = (const float*)d_in[1];
    const float* s_l = (const float*)d_in[2];
    const float* o_l = (const float*)d_in[3];
    const float* w_r = (const float*)d_in[4];
    const float* s_r = (const float*)d_in[5];
    const float* o_r = (const float*)d_in[6];
    const float* w_t = (const float*)d_in[7];
    const float* s_t = (const float*)d_in[8];
    const float* o_t = (const float*)d_in[9];
    const float* w_b = (const float*)d_in[10];
    const float* s_b = (const float*)d_in[11];
    const float* o_b = (const float*)d_in[12];
    const float* w2  = (const float*)d_in[13];
    const float* s2  = (const float*)d_in[14];
    const float* o2  = (const float*)d_in[15];
    const float* w1  = (const float*)d_in[16];
    const float* s1  = (const float*)d_in[17];
    const float* o1  = (const float*)d_in[18];
    float* out = (float*)d_out;
    char*  ws  = (char*)d_ws;

    unsigned short* xh    = (unsigned short*)(ws + 0);            // 64 MiB
    unsigned short* sbuf2 = (unsigned short*)(ws + 67108864);     // 32 MiB
    unsigned short* wpkBR = (unsigned short*)(ws + 100663296);    // 2.25 MiB
    unsigned short* wpk2  = (unsigned short*)(ws + 103022592);    // 576 KiB
    unsigned short* wpk1  = (unsigned short*)(ws + 103612416);    // 128 KiB
    float* shF = (float*)(ws + 103743488);
    float* obF = (float*)(ws + 103745536);

    unsigned short* ytbT = (unsigned short*)d_out;   // d_out as scratch (bf16, 2x32MiB)
    unsigned short* ytbB = ytbT + 16777216;

    dim3 blk(256);
    k_xpose<<<dim3(4, 128, 8), blk, 0, stream>>>(x, xh);
    k_wpack<<<dim3(6019), blk, 0, stream>>>(w_l, s_l, o_l, w_r, s_r, o_r,
                                            w_t, s_t, o_t, w_b, s_b, o_b,
                                            w2, s2, o2, w1, s1, o1,
                                            wpkBR, wpk2, wpk1, shF, obF);
    k_brconv<<<dim3(8, 32, 8), blk, 0, stream>>>(xh, wpkBR, shF, sbuf2, ytbT, ytbB);
    k_colscan2<<<dim3(8, 32), blk, 0, stream>>>(ytbT, ytbB, sbuf2);
    k_final<<<dim3(4, 32, 8), blk, 0, stream>>>(sbuf2, xh, wpk2, wpk1, obF, out);
}

// Round 8
// 670.326 us; speedup vs baseline: 1.2185x; 1.0109x over previous
//
#include <hip/hip_runtime.h>

#define NEG_INF (-3.402823466e+38f)

typedef __bf16 bf16x8 __attribute__((ext_vector_type(8)));
typedef float  f32x16 __attribute__((ext_vector_type(16)));

__device__ __forceinline__ unsigned short f2bf(float f){
    unsigned u = __builtin_bit_cast(unsigned, f);
    u += 0x7fffu + ((u >> 16) & 1u);
    return (unsigned short)(u >> 16);
}
__device__ __forceinline__ float bf2f(unsigned short h){
    unsigned u = ((unsigned)h) << 16;
    return __builtin_bit_cast(float, u);
}

#if defined(__has_builtin)
#if __has_builtin(__builtin_amdgcn_global_load_lds)
#define ASYNC_CP 1
#endif
#endif

// async global->LDS: per-lane g, wave-uniform lbase; lane i lands at lbase + i*16B
__device__ __forceinline__ void gl_lds(const unsigned short* g, unsigned short* lbase, int lane) {
#ifdef ASYNC_CP
    __builtin_amdgcn_global_load_lds(
        (const __attribute__((address_space(1))) unsigned int*)g,
        (__attribute__((address_space(3))) unsigned int*)lbase, 16, 0, 0);
#else
    *(uint4*)(lbase + (size_t)lane * 8) = *(const uint4*)g;
#endif
}

// ---------------- prep: x fp32 NCHW -> bf16 NHWC -------------------
__global__ void __launch_bounds__(256)
k_xpose(const float* __restrict__ x, unsigned short* __restrict__ xh)
{
    __shared__ float tile[64 * 129];
    const int t = threadIdx.x;
    const int ci0 = blockIdx.x * 64, h = blockIdx.y, b = blockIdx.z;
    const float4* src = (const float4*)x;
#pragma unroll
    for (int i = 0; i < 8; ++i) {
        int idx = t + i * 256;
        int ci = idx >> 5, w4 = idx & 31;
        float4 v = src[((b * 256 + ci0 + ci) * 128 + h) * 32 + w4];
        tile[ci * 129 + w4 * 4 + 0] = v.x;
        tile[ci * 129 + w4 * 4 + 1] = v.y;
        tile[ci * 129 + w4 * 4 + 2] = v.z;
        tile[ci * 129 + w4 * 4 + 3] = v.w;
    }
    __syncthreads();
    unsigned* dst = (unsigned*)xh;
#pragma unroll
    for (int i = 0; i < 16; ++i) {
        int idx = t + i * 256;
        int w = idx >> 5, cp = idx & 31;
        float lo = tile[(cp * 2 + 0) * 129 + w];
        float hi = tile[(cp * 2 + 1) * 129 + w];
        dst[((b * 128 + h) * 128 + w) * 128 + (ci0 >> 1) + cp] =
            (unsigned)f2bf(lo) | ((unsigned)f2bf(hi) << 16);
    }
}

// ---------------- prep: weight packing (BN scale folded) -----------
__global__ void __launch_bounds__(256)
k_wpack(const float* __restrict__ wl, const float* __restrict__ sl, const float* __restrict__ ol,
        const float* __restrict__ wr, const float* __restrict__ sr, const float* __restrict__ orr,
        const float* __restrict__ wt, const float* __restrict__ st, const float* __restrict__ ot,
        const float* __restrict__ wb, const float* __restrict__ sb, const float* __restrict__ ob,
        const float* __restrict__ w2, const float* __restrict__ s2, const float* __restrict__ o2,
        const float* __restrict__ w1, const float* __restrict__ s1, const float* __restrict__ o1,
        unsigned short* __restrict__ wpkBR, unsigned short* __restrict__ wpk2,
        unsigned short* __restrict__ wpk1, float* __restrict__ shF, float* __restrict__ obF)
{
    int i = blockIdx.x * 256 + threadIdx.x;
    if (i < 1179648) {
        int br = i / 294912, r = i % 294912;
        int c = r / 2304, r2 = r % 2304, ci = r2 / 9, k9 = r2 % 9;
        const float* wp = br == 0 ? wl : br == 1 ? wr : br == 2 ? wt : wb;
        const float* sp = br == 0 ? sl : br == 1 ? sr : br == 2 ? st : sb;
        float v = wp[r] * sp[c];
        int p = (c >> 4) * 64 + br * 16 + (c & 15);
        wpkBR[(((((ci >> 4) * 9 + k9) * 2 + ((ci >> 3) & 1)) * 512 + p) * 8) + (ci & 7)] = f2bf(v);
    } else if (i < 1474560) {
        int j = i - 1179648;
        int c = j / 1152, r2 = j % 1152, ci = r2 / 9, k9 = r2 % 9;
        wpk2[(((((ci >> 4) * 9 + k9) * 2 + ((ci >> 3) & 1)) * 256 + c) * 8) + (ci & 7)] = f2bf(w2[j] * s2[c]);
    } else if (i < 1540096) {
        int j = i - 1474560;
        int c = j >> 8, ci = j & 255;
        wpk1[((((ci >> 4) * 2 + ((ci >> 3) & 1)) * 256 + c) * 8) + (ci & 7)] = f2bf(w1[j] * s1[c]);
    } else if (i < 1540608) {
        int p = i - 1540096;
        int br = (p >> 4) & 3, c = (p >> 6) * 16 + (p & 15);
        const float* op = br == 0 ? ol : br == 1 ? orr : br == 2 ? ot : ob;
        shF[p] = op[c];
    } else if (i < 1540864) {
        int c = i - 1540608;
        obF[c] = o2[c] + o1[c];
    }
}

// ---------------- branch conv: all 4 branches, 4 rows/block --------
// r8 chunk restructure (same tile/occupancy as the 310-313us r2 kernel):
//  1. A-HOIST: 18 a-frags wbuf->regs at chunk start (72 VGPR). MFMA loop
//     then does only 36 b-reads -> LDS pipe (3.5K cyc) < MFMA (4.6K cyc)
//     during the compute phase (was 5.2K > 4.6K: co-limiting).
//  2. weights DMA'd straight into wbuf AFTER barrier#1 (wbuf free then) --
//     deletes the 5 global-load + 5 ds_write reg-bounce and its serial
//     write phase. DMAs overlap the MFMA phase, drained at barrier#2.
// A/B history: direct global A-frags = L1 thrash, 347us (r4). (256,3) =
// spill cliff, 1033us (r3). setprio = neutral, kept (r6).
// VGPR ~230 (acc 128 + af 72 + addr) < 256 cap -- watch WRITE_SIZE for
// spill evidence (should stay ~99MB).
#define XIN_SH 12672
#define WBUF_SH 9216
__global__ void __launch_bounds__(256, 2)
k_brconv(const unsigned short* __restrict__ xh, const unsigned short* __restrict__ wpkBR,
         const float* __restrict__ shF, unsigned short* __restrict__ sbuf2,
         unsigned short* __restrict__ ytbT, unsigned short* __restrict__ ytbB)
{
    __shared__ __align__(16) unsigned short smem[2 * XIN_SH + WBUF_SH + 128];
    unsigned short* xinA = smem;
    unsigned short* xinB = smem + XIN_SH;
    unsigned short* wbuf = smem + 2 * XIN_SH;
    float* shs = (float*)(smem + 2 * XIN_SH + WBUF_SH);

    const int t = threadIdx.x;
    // XCD-aware bijective swizzle (nwg=2048): XCD j works batch b=j.
    const int lin = (int)blockIdx.x + ((int)blockIdx.y << 3) + ((int)blockIdx.z << 8);
    const int swz = (lin & 7) * 256 + (lin >> 3);
    const int bx = swz & 7, h0 = ((swz >> 3) & 31) << 2, b = swz >> 8;
    const int wv = t >> 6, lane = t & 63;
    const int lo5 = lane & 31, hi1 = lane >> 5;
    const int hi32 = lane & 32;

    if (t < 64) shs[t] = shF[bx * 64 + t];
    // zero BOTH xin buffers once: halo cols + OOB rows stay zero forever
    for (int idx = t; idx < 3168; idx += 256)
        *(uint4*)(smem + idx * 8) = make_uint4(0, 0, 0, 0);

    f32x16 acc[2][4];
#pragma unroll
    for (int ct = 0; ct < 2; ++ct)
#pragma unroll
        for (int nb = 0; nb < 4; ++nb)
#pragma unroll
            for (int i = 0; i < 16; ++i) acc[ct][nb][i] = 0.f;

    __syncthreads();   // zero-init visible before async stores land

    // ---- prologue: stage chunk 0 (xin + weights via gl_lds) ----
    for (int s = wv; s < 24; s += 4) {
        int r = s >> 2, khi = (s >> 1) & 1, half = s & 1;
        int ih = h0 - 1 + r;
        if (ih >= 0 && ih < 128)
            gl_lds(xh + (((size_t)(b * 128 + ih) * 128 + half * 64 + lane) * 256) + khi * 8,
                   xinA + ((r * 2 + khi) * 132 + 1 + half * 64) * 8, lane);
    }
    for (int s = wv; s < 18; s += 4)
        gl_lds(wpkBR + ((size_t)s * 512 + bx * 64 + lane) * 8, wbuf + s * 512, lane);
    __syncthreads();

    unsigned short* xcur = xinA;
    unsigned short* xnxt = xinB;

    for (int cb = 0; cb < 16; ++cb) {
        // 1. A-HOIST: this chunk's a-frags LDS -> regs (lgkm path only)
        bf16x8 af0[9], af1[9];
#pragma unroll
        for (int k9 = 0; k9 < 9; ++k9) {
            af0[k9] = *(const bf16x8*)(wbuf + ((k9 * 2 + hi1) * 64 + lo5) * 8);
            af1[k9] = *(const bf16x8*)(wbuf + ((k9 * 2 + hi1) * 64 + 32 + lo5) * 8);
        }
        __syncthreads();   // #1: all waves done reading wbuf (vmcnt already 0)

        // 2. DMA next chunk's xin + weights (overlap the MFMA phase below)
        if (cb < 15) {
            const int nc = cb + 1;
            for (int s = wv; s < 24; s += 4) {
                int r = s >> 2, khi = (s >> 1) & 1, half = s & 1;
                int ih = h0 - 1 + r;
                if (ih >= 0 && ih < 128)
                    gl_lds(xh + (((size_t)(b * 128 + ih) * 128 + half * 64 + lane) * 256) + nc * 16 + khi * 8,
                           xnxt + ((r * 2 + khi) * 132 + 1 + half * 64) * 8, lane);
            }
            for (int s = wv; s < 18; s += 4)
                gl_lds(wpkBR + ((size_t)(nc * 18 + s) * 512 + bx * 64 + lane) * 8,
                       wbuf + s * 512, lane);
        }

        // 3. MFMA: a from regs, b from LDS (36 ds_reads)
        __builtin_amdgcn_s_setprio(1);
#pragma unroll
        for (int k9 = 0; k9 < 9; ++k9) {
            const int kh = k9 / 3, kw = k9 % 3;
#pragma unroll
            for (int nb = 0; nb < 4; ++nb) {
                bf16x8 bf = *(const bf16x8*)(xcur + (((wv + kh) * 2 + hi1) * 132 + nb * 32 + lo5 + kw) * 8);
                acc[0][nb] = __builtin_amdgcn_mfma_f32_32x32x16_bf16(af0[k9], bf, acc[0][nb], 0, 0, 0);
                acc[1][nb] = __builtin_amdgcn_mfma_f32_32x32x16_bf16(af1[k9], bf, acc[1][nb], 0, 0, 0);
            }
        }
        __builtin_amdgcn_s_setprio(0);
        __syncthreads();   // #2: drain DMAs; all waves done reading xcur
        unsigned short* tp = xcur; xcur = xnxt; xnxt = tp;
    }

    unsigned short* pbw = smem + wv * 3072;   // [w 128][c pad 24] bf16, per-wave
    const int hg = h0 + wv;

    // ---- L (ct0, regs 0..7): bias+relu then reverse cummax over w ----
#pragma unroll
    for (int r = 0; r < 8; ++r) {
        const int m = (r & 3) + 8 * (r >> 2) + 4 * hi1;
        const float shv = shs[m];
        float carry = NEG_INF;
#pragma unroll
        for (int nn = 3; nn >= 0; --nn) {
            float a = fmaxf(acc[0][nn][r] + shv, 0.f);
#pragma unroll
            for (int d = 1; d < 32; d <<= 1) {
                float o = __shfl_down(a, d);
                if (lo5 < 32 - d) a = fmaxf(a, o);
            }
            a = fmaxf(a, carry);
            carry = __shfl(a, hi32);
            acc[0][nn][r] = a;
        }
    }
    // ---- R (ct0, regs 8..15): forward cummax ----
#pragma unroll
    for (int r = 8; r < 16; ++r) {
        const int m = 16 + (r & 3) + 8 * ((r >> 2) & 1) + 4 * hi1;
        const float shv = shs[m];
        float carry = NEG_INF;
#pragma unroll
        for (int nn = 0; nn < 4; ++nn) {
            float a = fmaxf(acc[0][nn][r] + shv, 0.f);
#pragma unroll
            for (int d = 1; d < 32; d <<= 1) {
                float o = __shfl_up(a, d);
                if (lo5 >= d) a = fmaxf(a, o);
            }
            a = fmaxf(a, carry);
            carry = __shfl(a, hi32 | 31);
            acc[0][nn][r] = a;
        }
    }
    // ---- sum L+R -> pbw -> sbuf2 ----
#pragma unroll
    for (int r = 0; r < 8; ++r) {
        const int c16 = (r & 3) + 8 * (r >> 2) + 4 * hi1;
#pragma unroll
        for (int nn = 0; nn < 4; ++nn)
            pbw[(nn * 32 + lo5) * 24 + c16] = f2bf(acc[0][nn][r] + acc[0][nn][r + 8]);
    }
    {
        unsigned short* gdst = sbuf2 + ((size_t)(b * 128 + hg) * 128) * 128 + bx * 16;
#pragma unroll
        for (int i = 0; i < 4; ++i) {    // 256 uint4 segs = 128 w x 16 c
            int idx = lane + i * 64;
            int w = idx >> 1, part = idx & 1;
            *(uint4*)(gdst + (size_t)w * 128 + part * 8) = *(const uint4*)(pbw + w * 24 + part * 8);
        }
    }
    // ---- T (ct1, regs 0..7): bias+relu -> ytbT ----
#pragma unroll
    for (int r = 0; r < 8; ++r) {
        const int c16 = (r & 3) + 8 * (r >> 2) + 4 * hi1;
        const float shv = shs[32 + c16];
#pragma unroll
        for (int nn = 0; nn < 4; ++nn)
            pbw[(nn * 32 + lo5) * 24 + c16] = f2bf(fmaxf(acc[1][nn][r] + shv, 0.f));
    }
    {
        unsigned short* gdst = ytbT + ((size_t)(b * 128 + hg) * 128) * 128 + bx * 16;
#pragma unroll
        for (int i = 0; i < 4; ++i) {
            int idx = lane + i * 64;
            int w = idx >> 1, part = idx & 1;
            *(uint4*)(gdst + (size_t)w * 128 + part * 8) = *(const uint4*)(pbw + w * 24 + part * 8);
        }
    }
    // ---- B (ct1, regs 8..15): bias+relu -> ytbB ----
#pragma unroll
    for (int r = 8; r < 16; ++r) {
        const int c16 = (r & 3) + 8 * ((r >> 2) & 1) + 4 * hi1;
        const float shv = shs[48 + c16];
#pragma unroll
        for (int nn = 0; nn < 4; ++nn)
            pbw[(nn * 32 + lo5) * 24 + c16] = f2bf(fmaxf(acc[1][nn][r] + shv, 0.f));
    }
    {
        unsigned short* gdst = ytbB + ((size_t)(b * 128 + hg) * 128) * 128 + bx * 16;
#pragma unroll
        for (int i = 0; i < 4; ++i) {
            int idx = lane + i * 64;
            int w = idx >> 1, part = idx & 1;
            *(uint4*)(gdst + (size_t)w * 128 + part * 8) = *(const uint4*)(pbw + w * 24 + part * 8);
        }
    }
}

// -------- merged column scans: T (reverse) then B (forward), RMW sbuf2 ----
// r8: 1 channel/thread -> 131072 threads = 512 blocks = 2 blocks/CU =
// 2 waves/SIMD (r7 had 1 wave/SIMD: latency-bound serial chain walk needs
// the TLP). Wave's 64 lanes cover 64 consecutive channels = 128B bursts.
// Grid (8, 64): lin%8==b -> XCD j gets batch j (matches brconv locality).
__global__ void __launch_bounds__(256)
k_colscan2(const unsigned short* __restrict__ ytbT, const unsigned short* __restrict__ ytbB,
           unsigned short* __restrict__ sbuf2)
{
    const int t = threadIdx.x;
    const int b = blockIdx.x, wx = blockIdx.y;
    const int w = wx * 2 + (t >> 7), c = t & 127;
    const size_t hs = 128 * 128;                      // h stride (shorts)
    const size_t base = ((size_t)(b * 128) * 128 + w) * 128 + c;

    // pass 1: reverse cummax over ytbT, add into sbuf2
    {
        float cum = NEG_INF;
#pragma unroll 8
        for (int h = 127; h >= 0; --h) {
            cum = fmaxf(cum, bf2f(ytbT[base + (size_t)h * hs]));
            unsigned short* p = sbuf2 + base + (size_t)h * hs;
            *p = f2bf(bf2f(*p) + cum);
        }
    }
    // pass 2: forward cummax over ytbB, add into sbuf2
    {
        float cum = NEG_INF;
#pragma unroll 8
        for (int h = 0; h < 128; ++h) {
            cum = fmaxf(cum, bf2f(ytbB[base + (size_t)h * hs]));
            unsigned short* p = sbuf2 + base + (size_t)h * hs;
            *p = f2bf(bf2f(*p) + cum);
        }
    }
}

// ---------------- final: conv3x3(sbuf2,128->256) + 1x1(xh) ----------
// 3x3: r8 chunk restructure (a-hoist + weight DMA), as k_brconv.
// 1x1: fully register-direct (identity rearrangement, r4-verified).
// __launch_bounds__(256,2): spill cliff at 3 (r3 lesson).
__global__ void __launch_bounds__(256, 2)
k_final(const unsigned short* __restrict__ sbuf2, const unsigned short* __restrict__ xh,
        const unsigned short* __restrict__ wpk2, const unsigned short* __restrict__ wpk1,
        const float* __restrict__ obF, float* __restrict__ out)
{
    __shared__ __align__(16) unsigned short smem[2 * XIN_SH + WBUF_SH + 128];
    unsigned short* xinA = smem;
    unsigned short* xinB = smem + XIN_SH;
    unsigned short* wbuf = smem + 2 * XIN_SH;
    float* obs = (float*)(smem + 2 * XIN_SH + WBUF_SH);

    const int t = threadIdx.x;
    // XCD swizzle (nwg=1024): XCD j works batch b=j
    const int lin = (int)blockIdx.x + ((int)blockIdx.y << 2) + ((int)blockIdx.z << 7);
    const int swz = (lin & 7) * 128 + (lin >> 3);
    const int bx = swz & 3, h0 = ((swz >> 2) & 31) << 2, b = swz >> 7;
    const int wv = t >> 6, lane = t & 63;
    const int lo5 = lane & 31, hi1 = lane >> 5;

    if (t < 64) obs[t] = obF[bx * 64 + t];
    for (int idx = t; idx < 3168; idx += 256)
        *(uint4*)(smem + idx * 8) = make_uint4(0, 0, 0, 0);

    f32x16 acc[2][4];
#pragma unroll
    for (int ct = 0; ct < 2; ++ct)
#pragma unroll
        for (int nb = 0; nb < 4; ++nb)
#pragma unroll
            for (int i = 0; i < 16; ++i) acc[ct][nb][i] = 0.f;

    __syncthreads();

    // ---- prologue: stage 3x3 chunk 0 (xin + weights) ----
    for (int s = wv; s < 24; s += 4) {
        int r = s >> 2, khi = (s >> 1) & 1, half = s & 1;
        int ih = h0 - 1 + r;
        if (ih >= 0 && ih < 128)
            gl_lds(sbuf2 + (((size_t)(b * 128 + ih) * 128 + half * 64 + lane) * 128) + khi * 8,
                   xinA + ((r * 2 + khi) * 132 + 1 + half * 64) * 8, lane);
    }
    for (int s = wv; s < 18; s += 4)
        gl_lds(wpk2 + ((size_t)s * 256 + bx * 64 + lane) * 8, wbuf + s * 512, lane);
    __syncthreads();

    unsigned short* xcur = xinA;
    unsigned short* xnxt = xinB;

    // ---- 3x3 over sbuf2: 8 ci-chunks (a-hoist structure) ----
    for (int cb = 0; cb < 8; ++cb) {
        bf16x8 af0[9], af1[9];
#pragma unroll
        for (int k9 = 0; k9 < 9; ++k9) {
            af0[k9] = *(const bf16x8*)(wbuf + ((k9 * 2 + hi1) * 64 + lo5) * 8);
            af1[k9] = *(const bf16x8*)(wbuf + ((k9 * 2 + hi1) * 64 + 32 + lo5) * 8);
        }
        __syncthreads();   // #1

        if (cb < 7) {
            const int nc = cb + 1;
            for (int s = wv; s < 24; s += 4) {
                int r = s >> 2, khi = (s >> 1) & 1, half = s & 1;
                int ih = h0 - 1 + r;
                if (ih >= 0 && ih < 128)
                    gl_lds(sbuf2 + (((size_t)(b * 128 + ih) * 128 + half * 64 + lane) * 128) + nc * 16 + khi * 8,
                           xnxt + ((r * 2 + khi) * 132 + 1 + half * 64) * 8, lane);
            }
            for (int s = wv; s < 18; s += 4)
                gl_lds(wpk2 + ((size_t)(nc * 18 + s) * 256 + bx * 64 + lane) * 8,
                       wbuf + s * 512, lane);
        }

        __builtin_amdgcn_s_setprio(1);
#pragma unroll
        for (int k9 = 0; k9 < 9; ++k9) {
            const int kh = k9 / 3, kw = k9 % 3;
#pragma unroll
            for (int nb = 0; nb < 4; ++nb) {
                bf16x8 bf = *(const bf16x8*)(xcur + (((wv + kh) * 2 + hi1) * 132 + nb * 32 + lo5 + kw) * 8);
                acc[0][nb] = __builtin_amdgcn_mfma_f32_32x32x16_bf16(af0[k9], bf, acc[0][nb], 0, 0, 0);
                acc[1][nb] = __builtin_amdgcn_mfma_f32_32x32x16_bf16(af1[k9], bf, acc[1][nb], 0, 0, 0);
            }
        }
        __builtin_amdgcn_s_setprio(0);
        __syncthreads();   // #2
        unsigned short* tp = xcur; xcur = xnxt; xnxt = tp;
    }

    // ---- 1x1 over xh: direct global->reg, no LDS, no barriers ----
    {
        const unsigned short* xrow = xh + ((size_t)(b * 128 + h0 + wv) * 128) * 256 + hi1 * 8;
        const unsigned short* w1p  = wpk1 + ((size_t)hi1 * 256 + bx * 64) * 8;
#pragma unroll 4
        for (int cb = 0; cb < 16; ++cb) {
            bf16x8 a0 = *(const bf16x8*)(w1p + ((size_t)cb * 512 + lo5) * 8);
            bf16x8 a1 = *(const bf16x8*)(w1p + ((size_t)cb * 512 + 32 + lo5) * 8);
#pragma unroll
            for (int nb = 0; nb < 4; ++nb) {
                bf16x8 bf = *(const bf16x8*)(xrow + (size_t)(nb * 32 + lo5) * 256 + cb * 16);
                acc[0][nb] = __builtin_amdgcn_mfma_f32_32x32x16_bf16(a0, bf, acc[0][nb], 0, 0, 0);
                acc[1][nb] = __builtin_amdgcn_mfma_f32_32x32x16_bf16(a1, bf, acc[1][nb], 0, 0, 0);
            }
        }
    }

    // epilogue: bias + relu, fp32 NCHW stores (coalesced 32-lane segments)
    const int hg = h0 + wv;
#pragma unroll
    for (int ct = 0; ct < 2; ++ct)
#pragma unroll
        for (int r = 0; r < 16; ++r) {
            const int m = ct * 32 + (r & 3) + 8 * (r >> 2) + 4 * hi1;
            const float bias = obs[m];
#pragma unroll
            for (int nb = 0; nb < 4; ++nb)
                out[((size_t)(b * 256 + bx * 64 + m) * 128 + hg) * 128 + nb * 32 + lo5] =
                    fmaxf(acc[ct][nb][r] + bias, 0.f);
        }
}

extern "C" void kernel_launch(void* const* d_in, const int* in_sizes, int n_in,
                              void* d_out, int out_size, void* d_ws, size_t ws_size,
                              hipStream_t stream)
{
    const float* x   = (const float*)d_in[0];
    const float* w_l = (const float*)d_in[1];
    const float* s_l = (const float*)d_in[2];
    const float* o_l = (const float*)d_in[3];
    const float* w_r = (const float*)d_in[4];
    const float* s_r = (const float*)d_in[5];
    const float* o_r = (const float*)d_in[6];
    const float* w_t = (const float*)d_in[7];
    const float* s_t = (const float*)d_in[8];
    const float* o_t = (const float*)d_in[9];
    const float* w_b = (const float*)d_in[10];
    const float* s_b = (const float*)d_in[11];
    const float* o_b = (const float*)d_in[12];
    const float* w2  = (const float*)d_in[13];
    const float* s2  = (const float*)d_in[14];
    const float* o2  = (const float*)d_in[15];
    const float* w1  = (const float*)d_in[16];
    const float* s1  = (const float*)d_in[17];
    const float* o1  = (const float*)d_in[18];
    float* out = (float*)d_out;
    char*  ws  = (char*)d_ws;

    unsigned short* xh    = (unsigned short*)(ws + 0);            // 64 MiB
    unsigned short* sbuf2 = (unsigned short*)(ws + 67108864);     // 32 MiB
    unsigned short* wpkBR = (unsigned short*)(ws + 100663296);    // 2.25 MiB
    unsigned short* wpk2  = (unsigned short*)(ws + 103022592);    // 576 KiB
    unsigned short* wpk1  = (unsigned short*)(ws + 103612416);    // 128 KiB
    float* shF = (float*)(ws + 103743488);
    float* obF = (float*)(ws + 103745536);

    unsigned short* ytbT = (unsigned short*)d_out;   // d_out as scratch (bf16, 2x32MiB)
    unsigned short* ytbB = ytbT + 16777216;

    dim3 blk(256);
    k_xpose<<<dim3(4, 128, 8), blk, 0, stream>>>(x, xh);
    k_wpack<<<dim3(6019), blk, 0, stream>>>(w_l, s_l, o_l, w_r, s_r, o_r,
                                            w_t, s_t, o_t, w_b, s_b, o_b,
                                            w2, s2, o2, w1, s1, o1,
                                            wpkBR, wpk2, wpk1, shF, obF);
    k_brconv<<<dim3(8, 32, 8), blk, 0, stream>>>(xh, wpkBR, shF, sbuf2, ytbT, ytbB);
    k_colscan2<<<dim3(8, 64), blk, 0, stream>>>(ytbT, ytbB, sbuf2);
    k_final<<<dim3(4, 32, 8), blk, 0, stream>>>(sbuf2, xh, wpk2, wpk1, obF, out);
}